// Round 1
// baseline (3577.366 us; speedup 1.0000x reference)
//
#include <hip/hip_runtime.h>
#include <cstdint>
#include <cstddef>

// ---------------------------------------------------------------------------
// AdaAttN fused kernel set, fp16 MFMA path.
//   B=4, C=KP=512, N=M=4096.
//   ws layout (fp16): Fb[4][4096][512] | Gb[4][4096][512] | VT[4][1536][4096]
//     VT rows per batch: [0..511]   = Hs (v-hat, fp16)
//                        [512..1023]= fp16(v-hat^2)   (hi)
//                        [1024..1535]= v-hat^2 - hi    (lo)  -- protects e2-mean^2
//
// R4: de-serialize adaattn_flash.
//   * G LDS staging removed: each wave only ever consumed the rows it staged
//     itself, exactly once -> the DMA + drain + 2 barriers + 66.5 KB LDS +
//     1.9e7 bank conflicts bought nothing. QK B-fragments now read direct
//     from global (L2/L3-resident), same pattern as the (working) V loads.
//   * Per-wave V-column ownership regrouped to {g*512 + wv*128 ..+128},
//     g in {mean,hi,lo}: each wave holds the matching (mean,e2hi,e2lo)
//     triple for its own 128 channels -> epilogue fully in-register,
//     72 KB epilogue LDS union + its barriers deleted.
//   * LDS 73728 -> ~2.8 KB; launch_bounds(256,4): occupancy cap 2 -> 4
//     blocks/CU (VGPR=128 already fit). Barriers per M-tile: 4 -> 2.
//   NOTE: every loop touching acc[] MUST be fully unrolled -- a partial
//   unroll leaves a runtime index and demotes acc to scratch (R1/R2 bug).
// ---------------------------------------------------------------------------

typedef _Float16 f16;
typedef _Float16 f16x8 __attribute__((ext_vector_type(8)));
typedef float f32x4 __attribute__((ext_vector_type(4)));

#define LOG2E 1.44269504088896340736f

// ---------------------------------------------------------------------------
// conv_ik: out[b][i][k] = bias[k] + sum_c wm[k][c] * in[b][c][i]   (fp16 out)
// ---------------------------------------------------------------------------
__global__ __launch_bounds__(256, 2) void conv_ik(
    const float* __restrict__ in, const float* __restrict__ wm,
    const float* __restrict__ bias, f16* __restrict__ out) {
  const int i0 = blockIdx.x * 64;
  const int k0 = blockIdx.y * 64;
  const int b = blockIdx.z;
  const int tid = threadIdx.x;
  const int lane = tid & 63;
  const int wv = tid >> 6;
  const int l15 = lane & 15;
  const int quad = lane >> 4;

  __shared__ __align__(16) f16 a_lds[64 * 40];  // [i][c] stride 40 (pad)

  const float* inb = in + (size_t)b * (512 * 4096);

  f32x4 acc[4];
#pragma unroll
  for (int t = 0; t < 4; ++t) acc[t] = f32x4{0.f, 0.f, 0.f, 0.f};

  for (int cs = 0; cs < 512; cs += 32) {
    __syncthreads();
#pragma unroll
    for (int rep = 0; rep < 2; ++rep) {
      int chunk = tid + rep * 256;  // 0..511
      int cc = chunk >> 4;          // 0..31
      int f4 = chunk & 15;          // 0..15
      float4 v = *(const float4*)(inb + (size_t)(cs + cc) * 4096 + i0 + f4 * 4);
      int ib = f4 * 4;
      a_lds[(ib + 0) * 40 + cc] = (f16)v.x;
      a_lds[(ib + 1) * 40 + cc] = (f16)v.y;
      a_lds[(ib + 2) * 40 + cc] = (f16)v.z;
      a_lds[(ib + 3) * 40 + cc] = (f16)v.w;
    }
    __syncthreads();
    f16x8 af = *(const f16x8*)&a_lds[(wv * 16 + l15) * 40 + quad * 8];
#pragma unroll
    for (int ct = 0; ct < 4; ++ct) {
      const float* wp = wm + (size_t)(k0 + ct * 16 + l15) * 512 + cs + quad * 8;
      float4 w0 = *(const float4*)wp;
      float4 w1 = *(const float4*)(wp + 4);
      f16x8 bf;
      bf[0] = (f16)w0.x; bf[1] = (f16)w0.y; bf[2] = (f16)w0.z; bf[3] = (f16)w0.w;
      bf[4] = (f16)w1.x; bf[5] = (f16)w1.y; bf[6] = (f16)w1.z; bf[7] = (f16)w1.w;
      acc[ct] = __builtin_amdgcn_mfma_f32_16x16x32_f16(af, bf, acc[ct], 0, 0, 0);
    }
  }
#pragma unroll
  for (int ct = 0; ct < 4; ++ct) {
    int k = k0 + ct * 16 + l15;
    float bv = bias[k];
#pragma unroll
    for (int r = 0; r < 4; ++r) {
      int i = i0 + wv * 16 + quad * 4 + r;
      out[((size_t)b * 4096 + i) * 512 + k] = (f16)(acc[ct][r] + bv);
    }
  }
}

// ---------------------------------------------------------------------------
// conv_vt: val = bias[k] + sum_c wm[k][c] * in[b][c][i]
//   VT[b][k][i]=fp16(val); VT[b][512+k][i]=hi(val^2); VT[b][1024+k][i]=lo
// ---------------------------------------------------------------------------
__global__ __launch_bounds__(256, 2) void conv_vt(
    const float* __restrict__ in, const float* __restrict__ wm,
    const float* __restrict__ bias, f16* __restrict__ vt) {
  const int i0 = blockIdx.x * 64;
  const int k0 = blockIdx.y * 64;
  const int b = blockIdx.z;
  const int tid = threadIdx.x;
  const int lane = tid & 63;
  const int wv = tid >> 6;
  const int l15 = lane & 15;
  const int quad = lane >> 4;

  __shared__ __align__(16) f16 b_lds[64 * 40];  // [i][c] stride 40

  const float* inb = in + (size_t)b * (512 * 4096);

  f32x4 acc[4];
#pragma unroll
  for (int t = 0; t < 4; ++t) acc[t] = f32x4{0.f, 0.f, 0.f, 0.f};

  for (int cs = 0; cs < 512; cs += 32) {
    __syncthreads();
#pragma unroll
    for (int rep = 0; rep < 2; ++rep) {
      int chunk = tid + rep * 256;
      int cc = chunk >> 4;
      int f4 = chunk & 15;
      float4 v = *(const float4*)(inb + (size_t)(cs + cc) * 4096 + i0 + f4 * 4);
      int ib = f4 * 4;
      b_lds[(ib + 0) * 40 + cc] = (f16)v.x;
      b_lds[(ib + 1) * 40 + cc] = (f16)v.y;
      b_lds[(ib + 2) * 40 + cc] = (f16)v.z;
      b_lds[(ib + 3) * 40 + cc] = (f16)v.w;
    }
    __syncthreads();
    const float* wp = wm + (size_t)(k0 + wv * 16 + l15) * 512 + cs + quad * 8;
    float4 w0 = *(const float4*)wp;
    float4 w1 = *(const float4*)(wp + 4);
    f16x8 af;
    af[0] = (f16)w0.x; af[1] = (f16)w0.y; af[2] = (f16)w0.z; af[3] = (f16)w0.w;
    af[4] = (f16)w1.x; af[5] = (f16)w1.y; af[6] = (f16)w1.z; af[7] = (f16)w1.w;
#pragma unroll
    for (int ct = 0; ct < 4; ++ct) {
      f16x8 bfr = *(const f16x8*)&b_lds[(ct * 16 + l15) * 40 + quad * 8];
      acc[ct] = __builtin_amdgcn_mfma_f32_16x16x32_f16(af, bfr, acc[ct], 0, 0, 0);
    }
  }
  f16* vtb = vt + (size_t)b * 1536 * 4096;
#pragma unroll
  for (int ct = 0; ct < 4; ++ct) {
    int i = i0 + ct * 16 + l15;
#pragma unroll
    for (int r = 0; r < 4; ++r) {
      int k = k0 + wv * 16 + quad * 4 + r;
      float val = acc[ct][r] + bias[k];
      f16 vh = (f16)val;
      float vf = (float)vh;
      float sq = vf * vf;
      f16 sqh = (f16)sq;
      f16 sql = (f16)(sq - (float)sqh);
      vtb[(size_t)k * 4096 + i] = vh;
      vtb[(size_t)(512 + k) * 4096 + i] = sqh;
      vtb[(size_t)(1024 + k) * 4096 + i] = sql;
    }
  }
}

// ---------------------------------------------------------------------------
// adaattn_flash: per block = 16 Q-rows of one batch; 4 waves; M-tiles of 64.
//   wave w owns V rows {g*512 + w*128 .. +128} for g in {mean,hi,lo}
//   (24 16x16 acc tiles, 96 regs) -> epilogue is wave-local, no LDS.
//   F fragments read from global (16 KB tile, L1-resident).
//   G fragments read from global (L2/L3-resident; no reuse -> no staging).
//   V read from global (L2/L3-resident).
//   LDS: p_lds (P exchange, cross-wave) + smax/ssum only (~2.8 KB).
//   2 barriers per M-tile. 4 blocks/CU (VGPR-capped at 128).
// ---------------------------------------------------------------------------

// PV over one V-row group; G must be a literal so acc indices stay constant.
#define PV_GROUP(G, BASE)                                                     \
  {                                                                           \
    const f16* vp = (BASE) + m0 + quad * 8;                                   \
    _Pragma("unroll")                                                         \
    for (int ct = 0; ct < 8; ++ct) {                                          \
      f16x8 v0 = *(const f16x8*)(vp + (size_t)ct * (16 * 4096));              \
      f16x8 v1 = *(const f16x8*)(vp + (size_t)ct * (16 * 4096) + 32);         \
      acc[(G) * 8 + ct] =                                                     \
          __builtin_amdgcn_mfma_f32_16x16x32_f16(pf0, v0, acc[(G) * 8 + ct],  \
                                                 0, 0, 0);                    \
      acc[(G) * 8 + ct] =                                                     \
          __builtin_amdgcn_mfma_f32_16x16x32_f16(pf1, v1, acc[(G) * 8 + ct],  \
                                                 0, 0, 0);                    \
    }                                                                         \
  }

__global__ __launch_bounds__(256, 4) void adaattn_flash(
    const f16* __restrict__ Fb, const f16* __restrict__ Gb,
    const f16* __restrict__ VT, const float* __restrict__ cx,
    float* __restrict__ out) {
  const int n0 = blockIdx.x * 16;
  const int b = blockIdx.y;
  const int tid = threadIdx.x;
  const int lane = tid & 63;
  const int wv = tid >> 6;
  const int l15 = lane & 15;
  const int quad = lane >> 4;

  __shared__ __align__(16) f16 p_lds[16 * 72];  // [qrow][mcol] stride 72
  __shared__ float smax[64];                    // [wave][qrow]
  __shared__ float ssum[64];                    // [wave][qrow]

  // F A-fragment base: A[m=l15][k=quad*8+j]; re-read per K-step (L1-hot)
  const f16* fp = Fb + ((size_t)b * 4096 + n0 + l15) * 512 + quad * 8;
  // G B-fragment base for this wave's 16 logit columns (direct global)
  const f16* gq0 = Gb + ((size_t)b * 4096 + wv * 16 + l15) * 512 + quad * 8;
  // V row-group bases: wave's own 128-channel slice of mean / e2hi / e2lo
  const f16* vb0 = VT + ((size_t)b * 1536 + (size_t)wv * 128 + l15) * 4096;
  const f16* vb1 = vb0 + (size_t)512 * 4096;
  const f16* vb2 = vb1 + (size_t)512 * 4096;

  f32x4 acc[24];
#pragma unroll
  for (int t = 0; t < 24; ++t) acc[t] = f32x4{0.f, 0.f, 0.f, 0.f};
  float m_run[4] = {-1e30f, -1e30f, -1e30f, -1e30f};
  float l_run[4] = {0.f, 0.f, 0.f, 0.f};

  for (int m0 = 0; m0 < 4096; m0 += 64) {
    // QK: wave w -> logit cols [w*16, w*16+16), K=512, operands from global
    f32x4 lg = f32x4{0.f, 0.f, 0.f, 0.f};
    {
      const f16* gq = gq0 + (size_t)m0 * 512;
#pragma unroll 8
      for (int ks = 0; ks < 16; ++ks) {
        f16x8 gf = *(const f16x8*)(gq + ks * 32);
        f16x8 ff = *(const f16x8*)(fp + ks * 32);
        lg = __builtin_amdgcn_mfma_f32_16x16x32_f16(ff, gf, lg, 0, 0, 0);
      }
    }

    // wave-local row max over this wave's 16 cols (butterfly in 16-lane grp)
    float tm[4];
#pragma unroll
    for (int r = 0; r < 4; ++r) {
      float v = lg[r];
      v = fmaxf(v, __shfl_xor(v, 1));
      v = fmaxf(v, __shfl_xor(v, 2));
      v = fmaxf(v, __shfl_xor(v, 4));
      v = fmaxf(v, __shfl_xor(v, 8));
      tm[r] = v;
    }
    if (l15 == 0) {
#pragma unroll
      for (int r = 0; r < 4; ++r) smax[wv * 16 + quad * 4 + r] = tm[r];
    }
    __syncthreads();  // bar1: smax complete; also fences prev-iter p_lds reads

    float alpha[4], ts[4];
#pragma unroll
    for (int r = 0; r < 4; ++r) {
      int row = quad * 4 + r;
      float mt = fmaxf(fmaxf(smax[row], smax[16 + row]),
                       fmaxf(smax[32 + row], smax[48 + row]));
      float mn = fmaxf(m_run[r], mt);
      alpha[r] = exp2f((m_run[r] - mn) * LOG2E);
      m_run[r] = mn;
      float p = exp2f((lg[r] - mn) * LOG2E);
      f16 ph = (f16)p;     // round first so weights & sums agree exactly
      p = (float)ph;
      p_lds[row * 72 + wv * 16 + l15] = ph;
      float s = p;
      s += __shfl_xor(s, 1);
      s += __shfl_xor(s, 2);
      s += __shfl_xor(s, 4);
      s += __shfl_xor(s, 8);
      ts[r] = s;
    }
    if (l15 == 0) {
#pragma unroll
      for (int r = 0; r < 4; ++r) ssum[wv * 16 + quad * 4 + r] = ts[r];
    }
    // rescale accumulators by alpha (per-row); skip when all alpha == 1
    if (__any(alpha[0] != 1.f || alpha[1] != 1.f ||
              alpha[2] != 1.f || alpha[3] != 1.f)) {
#pragma unroll
      for (int t = 0; t < 24; ++t) {
#pragma unroll
        for (int r = 0; r < 4; ++r) acc[t][r] *= alpha[r];
      }
    }
    __syncthreads();  // bar2: p_lds + ssum complete

#pragma unroll
    for (int r = 0; r < 4; ++r) {
      int row = quad * 4 + r;
      l_run[r] = l_run[r] * alpha[r] +
                 (ssum[row] + ssum[16 + row] + ssum[32 + row] + ssum[48 + row]);
    }

    // PV: A = P (from LDS, cross-wave), B = VT rows direct from global.
    // FULL unroll: constant acc indices (partial unroll => scratch demotion)
    f16x8 pf0 = *(const f16x8*)&p_lds[l15 * 72 + quad * 8];
    f16x8 pf1 = *(const f16x8*)&p_lds[l15 * 72 + 32 + quad * 8];
    PV_GROUP(0, vb0)
    PV_GROUP(1, vb1)
    PV_GROUP(2, vb2)
  }

  // ---------------- epilogue (wave-local, no LDS, no barriers) ------------
  float inv_[4];
#pragma unroll
  for (int r = 0; r < 4; ++r) inv_[r] = 1.0f / l_run[r];

  const size_t base = ((size_t)b * 512) * 4096 + n0 + quad * 4;
#pragma unroll
  for (int ct = 0; ct < 8; ++ct) {
    int c = wv * 128 + ct * 16 + l15;
    size_t off = base + (size_t)c * 4096;
    f32x4 cxv = *(const f32x4*)(cx + off);
    f32x4 o;
#pragma unroll
    for (int r = 0; r < 4; ++r) {
      float m = acc[ct][r] * inv_[r];
      float e2 = (acc[8 + ct][r] + acc[16 + ct][r]) * inv_[r];
      float sd = sqrtf(fmaxf(e2 - m * m, 0.f));
      o[r] = sd * cxv[r] + m;
    }
    *(f32x4*)(out + off) = o;
  }
}

// ---------------------------------------------------------------------------
extern "C" void kernel_launch(void* const* d_in, const int* in_sizes, int n_in,
                              void* d_out, int out_size, void* d_ws, size_t ws_size,
                              hipStream_t stream) {
  (void)in_sizes; (void)n_in; (void)out_size;
  const float* c_x  = (const float*)d_in[0];
  const float* s_x  = (const float*)d_in[1];
  const float* c_1x = (const float*)d_in[2];
  const float* s_1x = (const float*)d_in[3];
  const float* f_w  = (const float*)d_in[4];
  const float* f_b  = (const float*)d_in[5];
  const float* g_w  = (const float*)d_in[6];
  const float* g_b  = (const float*)d_in[7];
  const float* h_w  = (const float*)d_in[8];
  const float* h_b  = (const float*)d_in[9];
  float* out = (float*)d_out;

  const size_t fe = (size_t)4 * 4096 * 512;  // elements per F/G buffer
  f16* Fb = (f16*)d_ws;
  f16* Gb = Fb + fe;
  f16* VT = Gb + fe;
  const size_t need = fe * 2 * sizeof(f16) * 2 + (size_t)4 * 1536 * 4096 * sizeof(f16);
  if (ws_size < need) return;  // 80 MiB required; fail loudly (output stays poisoned)

  dim3 blk(256);
  dim3 gP(64, 8, 4);
  conv_ik<<<gP, blk, 0, stream>>>(c_1x, f_w, f_b, Fb);
  conv_ik<<<gP, blk, 0, stream>>>(s_1x, g_w, g_b, Gb);
  conv_vt<<<gP, blk, 0, stream>>>(s_x, h_w, h_b, VT);
  adaattn_flash<<<dim3(256, 4), blk, 0, stream>>>(Fb, Gb, VT, c_x, out);
}

// Round 2
// 2806.042 us; speedup vs baseline: 1.2749x; 1.2749x over previous
//
#include <hip/hip_runtime.h>
#include <cstdint>
#include <cstddef>

// ---------------------------------------------------------------------------
// AdaAttN fused kernel set, fp16 MFMA path.
//   B=4, C=KP=512, N=M=4096.
//   ws layout (fp16): Fb[4][4096][512] | Gb[4][4096][512] | VT[4][1536][4096]
//     VT rows per batch: [0..511]   = Hs (v-hat, fp16)
//                        [512..1023]= fp16(v-hat^2)   (hi)
//                        [1024..1535]= v-hat^2 - hi    (lo)  -- protects e2-mean^2
//
// R5: fix R4's spill catastrophe.
//   R4 post-mortem: __launch_bounds__(256,4) capped VGPR at 128 < ~140 live
//   demand -> allocator spilled acc[24] to scratch (VGPR_Count=64,
//   WRITE_SIZE 5.6 GB = 96 regs x 4B x 256thr x 64 tiles x 1024 blocks).
//   Fixes:
//   * e2-hi and e2-lo accumulate into the SAME f32 acc tile (MFMA C is
//     in/out): acc 24 -> 16 tiles (96 -> 64 VGPRs), identical math up to
//     f32 add order. Same MFMA count; rescale loop 96 -> 64 mults.
//   * __launch_bounds__(256,3): reg cap ~168 >> demand (~110) -> no spill;
//     >=3 blocks/CU, HW gives 4 if allocation lands <=128.
//   Kept from R4 (these were right): no G staging (zero reuse), wave-local
//   epilogue (no 72KB LDS union), LDS ~2.8KB, 2 barriers/M-tile.
//   NOTE: every loop touching acc[] MUST be fully unrolled -- a partial
//   unroll leaves a runtime index and demotes acc to scratch (R1/R2 bug).
// ---------------------------------------------------------------------------

typedef _Float16 f16;
typedef _Float16 f16x8 __attribute__((ext_vector_type(8)));
typedef float f32x4 __attribute__((ext_vector_type(4)));

#define LOG2E 1.44269504088896340736f

// ---------------------------------------------------------------------------
// conv_ik: out[b][i][k] = bias[k] + sum_c wm[k][c] * in[b][c][i]   (fp16 out)
// ---------------------------------------------------------------------------
__global__ __launch_bounds__(256, 2) void conv_ik(
    const float* __restrict__ in, const float* __restrict__ wm,
    const float* __restrict__ bias, f16* __restrict__ out) {
  const int i0 = blockIdx.x * 64;
  const int k0 = blockIdx.y * 64;
  const int b = blockIdx.z;
  const int tid = threadIdx.x;
  const int lane = tid & 63;
  const int wv = tid >> 6;
  const int l15 = lane & 15;
  const int quad = lane >> 4;

  __shared__ __align__(16) f16 a_lds[64 * 40];  // [i][c] stride 40 (pad)

  const float* inb = in + (size_t)b * (512 * 4096);

  f32x4 acc[4];
#pragma unroll
  for (int t = 0; t < 4; ++t) acc[t] = f32x4{0.f, 0.f, 0.f, 0.f};

  for (int cs = 0; cs < 512; cs += 32) {
    __syncthreads();
#pragma unroll
    for (int rep = 0; rep < 2; ++rep) {
      int chunk = tid + rep * 256;  // 0..511
      int cc = chunk >> 4;          // 0..31
      int f4 = chunk & 15;          // 0..15
      float4 v = *(const float4*)(inb + (size_t)(cs + cc) * 4096 + i0 + f4 * 4);
      int ib = f4 * 4;
      a_lds[(ib + 0) * 40 + cc] = (f16)v.x;
      a_lds[(ib + 1) * 40 + cc] = (f16)v.y;
      a_lds[(ib + 2) * 40 + cc] = (f16)v.z;
      a_lds[(ib + 3) * 40 + cc] = (f16)v.w;
    }
    __syncthreads();
    f16x8 af = *(const f16x8*)&a_lds[(wv * 16 + l15) * 40 + quad * 8];
#pragma unroll
    for (int ct = 0; ct < 4; ++ct) {
      const float* wp = wm + (size_t)(k0 + ct * 16 + l15) * 512 + cs + quad * 8;
      float4 w0 = *(const float4*)wp;
      float4 w1 = *(const float4*)(wp + 4);
      f16x8 bf;
      bf[0] = (f16)w0.x; bf[1] = (f16)w0.y; bf[2] = (f16)w0.z; bf[3] = (f16)w0.w;
      bf[4] = (f16)w1.x; bf[5] = (f16)w1.y; bf[6] = (f16)w1.z; bf[7] = (f16)w1.w;
      acc[ct] = __builtin_amdgcn_mfma_f32_16x16x32_f16(af, bf, acc[ct], 0, 0, 0);
    }
  }
#pragma unroll
  for (int ct = 0; ct < 4; ++ct) {
    int k = k0 + ct * 16 + l15;
    float bv = bias[k];
#pragma unroll
    for (int r = 0; r < 4; ++r) {
      int i = i0 + wv * 16 + quad * 4 + r;
      out[((size_t)b * 4096 + i) * 512 + k] = (f16)(acc[ct][r] + bv);
    }
  }
}

// ---------------------------------------------------------------------------
// conv_vt: val = bias[k] + sum_c wm[k][c] * in[b][c][i]
//   VT[b][k][i]=fp16(val); VT[b][512+k][i]=hi(val^2); VT[b][1024+k][i]=lo
// ---------------------------------------------------------------------------
__global__ __launch_bounds__(256, 2) void conv_vt(
    const float* __restrict__ in, const float* __restrict__ wm,
    const float* __restrict__ bias, f16* __restrict__ vt) {
  const int i0 = blockIdx.x * 64;
  const int k0 = blockIdx.y * 64;
  const int b = blockIdx.z;
  const int tid = threadIdx.x;
  const int lane = tid & 63;
  const int wv = tid >> 6;
  const int l15 = lane & 15;
  const int quad = lane >> 4;

  __shared__ __align__(16) f16 b_lds[64 * 40];  // [i][c] stride 40

  const float* inb = in + (size_t)b * (512 * 4096);

  f32x4 acc[4];
#pragma unroll
  for (int t = 0; t < 4; ++t) acc[t] = f32x4{0.f, 0.f, 0.f, 0.f};

  for (int cs = 0; cs < 512; cs += 32) {
    __syncthreads();
#pragma unroll
    for (int rep = 0; rep < 2; ++rep) {
      int chunk = tid + rep * 256;
      int cc = chunk >> 4;
      int f4 = chunk & 15;
      float4 v = *(const float4*)(inb + (size_t)(cs + cc) * 4096 + i0 + f4 * 4);
      int ib = f4 * 4;
      b_lds[(ib + 0) * 40 + cc] = (f16)v.x;
      b_lds[(ib + 1) * 40 + cc] = (f16)v.y;
      b_lds[(ib + 2) * 40 + cc] = (f16)v.z;
      b_lds[(ib + 3) * 40 + cc] = (f16)v.w;
    }
    __syncthreads();
    const float* wp = wm + (size_t)(k0 + wv * 16 + l15) * 512 + cs + quad * 8;
    float4 w0 = *(const float4*)wp;
    float4 w1 = *(const float4*)(wp + 4);
    f16x8 af;
    af[0] = (f16)w0.x; af[1] = (f16)w0.y; af[2] = (f16)w0.z; af[3] = (f16)w0.w;
    af[4] = (f16)w1.x; af[5] = (f16)w1.y; af[6] = (f16)w1.z; af[7] = (f16)w1.w;
#pragma unroll
    for (int ct = 0; ct < 4; ++ct) {
      f16x8 bfr = *(const f16x8*)&b_lds[(ct * 16 + l15) * 40 + quad * 8];
      acc[ct] = __builtin_amdgcn_mfma_f32_16x16x32_f16(af, bfr, acc[ct], 0, 0, 0);
    }
  }
  f16* vtb = vt + (size_t)b * 1536 * 4096;
#pragma unroll
  for (int ct = 0; ct < 4; ++ct) {
    int i = i0 + ct * 16 + l15;
#pragma unroll
    for (int r = 0; r < 4; ++r) {
      int k = k0 + wv * 16 + quad * 4 + r;
      float val = acc[ct][r] + bias[k];
      f16 vh = (f16)val;
      float vf = (float)vh;
      float sq = vf * vf;
      f16 sqh = (f16)sq;
      f16 sql = (f16)(sq - (float)sqh);
      vtb[(size_t)k * 4096 + i] = vh;
      vtb[(size_t)(512 + k) * 4096 + i] = sqh;
      vtb[(size_t)(1024 + k) * 4096 + i] = sql;
    }
  }
}

// ---------------------------------------------------------------------------
// adaattn_flash: per block = 16 Q-rows of one batch; 4 waves; M-tiles of 64.
//   wave w owns V channels [w*128, w*128+128): acc[0..7] = mean tiles,
//   acc[8..15] = e2 tiles (hi and lo MFMAs both accumulate there).
//   Epilogue wave-local, no LDS. F/G/V fragments direct from global
//   (L1/L2/L3-resident). LDS: p_lds + smax/ssum (~2.8 KB).
//   2 barriers per M-tile. Reg demand ~110; launch_bounds(256,3) cap ~168.
// ---------------------------------------------------------------------------
__global__ __launch_bounds__(256, 3) void adaattn_flash(
    const f16* __restrict__ Fb, const f16* __restrict__ Gb,
    const f16* __restrict__ VT, const float* __restrict__ cx,
    float* __restrict__ out) {
  const int n0 = blockIdx.x * 16;
  const int b = blockIdx.y;
  const int tid = threadIdx.x;
  const int lane = tid & 63;
  const int wv = tid >> 6;
  const int l15 = lane & 15;
  const int quad = lane >> 4;

  __shared__ __align__(16) f16 p_lds[16 * 72];  // [qrow][mcol] stride 72
  __shared__ float smax[64];                    // [wave][qrow]
  __shared__ float ssum[64];                    // [wave][qrow]

  // F A-fragment base: A[m=l15][k=quad*8+j]; re-read per K-step (L1-hot)
  const f16* fp = Fb + ((size_t)b * 4096 + n0 + l15) * 512 + quad * 8;
  // G B-fragment base for this wave's 16 logit columns (direct global)
  const f16* gq0 = Gb + ((size_t)b * 4096 + wv * 16 + l15) * 512 + quad * 8;
  // V row-group bases: wave's own 128-channel slice of mean / e2hi / e2lo
  const f16* vb0 = VT + ((size_t)b * 1536 + (size_t)wv * 128 + l15) * 4096;
  const f16* vb1 = vb0 + (size_t)512 * 4096;
  const f16* vb2 = vb1 + (size_t)512 * 4096;

  f32x4 acc[16];
#pragma unroll
  for (int t = 0; t < 16; ++t) acc[t] = f32x4{0.f, 0.f, 0.f, 0.f};
  float m_run[4] = {-1e30f, -1e30f, -1e30f, -1e30f};
  float l_run[4] = {0.f, 0.f, 0.f, 0.f};

  for (int m0 = 0; m0 < 4096; m0 += 64) {
    // QK: wave w -> logit cols [w*16, w*16+16), K=512, operands from global
    f32x4 lg = f32x4{0.f, 0.f, 0.f, 0.f};
    {
      const f16* gq = gq0 + (size_t)m0 * 512;
#pragma unroll 8
      for (int ks = 0; ks < 16; ++ks) {
        f16x8 gf = *(const f16x8*)(gq + ks * 32);
        f16x8 ff = *(const f16x8*)(fp + ks * 32);
        lg = __builtin_amdgcn_mfma_f32_16x16x32_f16(ff, gf, lg, 0, 0, 0);
      }
    }

    // wave-local row max over this wave's 16 cols (butterfly in 16-lane grp)
    float tm[4];
#pragma unroll
    for (int r = 0; r < 4; ++r) {
      float v = lg[r];
      v = fmaxf(v, __shfl_xor(v, 1));
      v = fmaxf(v, __shfl_xor(v, 2));
      v = fmaxf(v, __shfl_xor(v, 4));
      v = fmaxf(v, __shfl_xor(v, 8));
      tm[r] = v;
    }
    if (l15 == 0) {
#pragma unroll
      for (int r = 0; r < 4; ++r) smax[wv * 16 + quad * 4 + r] = tm[r];
    }
    __syncthreads();  // bar1: smax complete; also fences prev-iter p_lds reads

    float alpha[4], ts[4];
#pragma unroll
    for (int r = 0; r < 4; ++r) {
      int row = quad * 4 + r;
      float mt = fmaxf(fmaxf(smax[row], smax[16 + row]),
                       fmaxf(smax[32 + row], smax[48 + row]));
      float mn = fmaxf(m_run[r], mt);
      alpha[r] = exp2f((m_run[r] - mn) * LOG2E);
      m_run[r] = mn;
      float p = exp2f((lg[r] - mn) * LOG2E);
      f16 ph = (f16)p;     // round first so weights & sums agree exactly
      p = (float)ph;
      p_lds[row * 72 + wv * 16 + l15] = ph;
      float s = p;
      s += __shfl_xor(s, 1);
      s += __shfl_xor(s, 2);
      s += __shfl_xor(s, 4);
      s += __shfl_xor(s, 8);
      ts[r] = s;
    }
    if (l15 == 0) {
#pragma unroll
      for (int r = 0; r < 4; ++r) ssum[wv * 16 + quad * 4 + r] = ts[r];
    }
    // rescale accumulators by alpha (per-row); skip when all alpha == 1
    if (__any(alpha[0] != 1.f || alpha[1] != 1.f ||
              alpha[2] != 1.f || alpha[3] != 1.f)) {
#pragma unroll
      for (int t = 0; t < 16; ++t) {
#pragma unroll
        for (int r = 0; r < 4; ++r) acc[t][r] *= alpha[r];
      }
    }
    __syncthreads();  // bar2: p_lds + ssum complete

#pragma unroll
    for (int r = 0; r < 4; ++r) {
      int row = quad * 4 + r;
      l_run[r] = l_run[r] * alpha[r] +
                 (ssum[row] + ssum[16 + row] + ssum[32 + row] + ssum[48 + row]);
    }

    // PV: A = P (from LDS, cross-wave), B = VT rows direct from global.
    // mean -> acc[ct]; e2 hi AND lo -> acc[8+ct] (MFMA C is in/out).
    // FULL unroll: constant acc indices (partial unroll => scratch demotion)
    f16x8 pf0 = *(const f16x8*)&p_lds[l15 * 72 + quad * 8];
    f16x8 pf1 = *(const f16x8*)&p_lds[l15 * 72 + 32 + quad * 8];
    const f16* vpm = vb0 + m0 + quad * 8;
    const f16* vph = vb1 + m0 + quad * 8;
    const f16* vpl = vb2 + m0 + quad * 8;
#pragma unroll
    for (int ct = 0; ct < 8; ++ct) {
      const size_t o = (size_t)ct * (16 * 4096);
      f16x8 vm0 = *(const f16x8*)(vpm + o);
      f16x8 vm1 = *(const f16x8*)(vpm + o + 32);
      acc[ct] = __builtin_amdgcn_mfma_f32_16x16x32_f16(pf0, vm0, acc[ct], 0, 0, 0);
      acc[ct] = __builtin_amdgcn_mfma_f32_16x16x32_f16(pf1, vm1, acc[ct], 0, 0, 0);
      f16x8 vh0 = *(const f16x8*)(vph + o);
      f16x8 vh1 = *(const f16x8*)(vph + o + 32);
      acc[8 + ct] = __builtin_amdgcn_mfma_f32_16x16x32_f16(pf0, vh0, acc[8 + ct], 0, 0, 0);
      acc[8 + ct] = __builtin_amdgcn_mfma_f32_16x16x32_f16(pf1, vh1, acc[8 + ct], 0, 0, 0);
      f16x8 vl0 = *(const f16x8*)(vpl + o);
      f16x8 vl1 = *(const f16x8*)(vpl + o + 32);
      acc[8 + ct] = __builtin_amdgcn_mfma_f32_16x16x32_f16(pf0, vl0, acc[8 + ct], 0, 0, 0);
      acc[8 + ct] = __builtin_amdgcn_mfma_f32_16x16x32_f16(pf1, vl1, acc[8 + ct], 0, 0, 0);
    }
  }

  // ---------------- epilogue (wave-local, no LDS, no barriers) ------------
  float inv_[4];
#pragma unroll
  for (int r = 0; r < 4; ++r) inv_[r] = 1.0f / l_run[r];

  const size_t base = ((size_t)b * 512) * 4096 + n0 + quad * 4;
#pragma unroll
  for (int ct = 0; ct < 8; ++ct) {
    int c = wv * 128 + ct * 16 + l15;
    size_t off = base + (size_t)c * 4096;
    f32x4 cxv = *(const f32x4*)(cx + off);
    f32x4 o;
#pragma unroll
    for (int r = 0; r < 4; ++r) {
      float m = acc[ct][r] * inv_[r];
      float e2 = acc[8 + ct][r] * inv_[r];
      float sd = sqrtf(fmaxf(e2 - m * m, 0.f));
      o[r] = sd * cxv[r] + m;
    }
    *(f32x4*)(out + off) = o;
  }
}

// ---------------------------------------------------------------------------
extern "C" void kernel_launch(void* const* d_in, const int* in_sizes, int n_in,
                              void* d_out, int out_size, void* d_ws, size_t ws_size,
                              hipStream_t stream) {
  (void)in_sizes; (void)n_in; (void)out_size;
  const float* c_x  = (const float*)d_in[0];
  const float* s_x  = (const float*)d_in[1];
  const float* c_1x = (const float*)d_in[2];
  const float* s_1x = (const float*)d_in[3];
  const float* f_w  = (const float*)d_in[4];
  const float* f_b  = (const float*)d_in[5];
  const float* g_w  = (const float*)d_in[6];
  const float* g_b  = (const float*)d_in[7];
  const float* h_w  = (const float*)d_in[8];
  const float* h_b  = (const float*)d_in[9];
  float* out = (float*)d_out;

  const size_t fe = (size_t)4 * 4096 * 512;  // elements per F/G buffer
  f16* Fb = (f16*)d_ws;
  f16* Gb = Fb + fe;
  f16* VT = Gb + fe;
  const size_t need = fe * 2 * sizeof(f16) * 2 + (size_t)4 * 1536 * 4096 * sizeof(f16);
  if (ws_size < need) return;  // 80 MiB required; fail loudly (output stays poisoned)

  dim3 blk(256);
  dim3 gP(64, 8, 4);
  conv_ik<<<gP, blk, 0, stream>>>(c_1x, f_w, f_b, Fb);
  conv_ik<<<gP, blk, 0, stream>>>(s_1x, g_w, g_b, Gb);
  conv_vt<<<gP, blk, 0, stream>>>(s_x, h_w, h_b, VT);
  adaattn_flash<<<dim3(256, 4), blk, 0, stream>>>(Fb, Gb, VT, c_x, out);
}

// Round 4
// 2283.377 us; speedup vs baseline: 1.5667x; 1.2289x over previous
//
#include <hip/hip_runtime.h>
#include <cstdint>
#include <cstddef>

// ---------------------------------------------------------------------------
// AdaAttN fused kernel set, fp16 MFMA path.
//   B=4, C=KP=512, N=M=4096.
//   ws layout (fp16): Fb[4][4096][512] | Gb[4][4096][512] | VT[4][1536][4096]
//     VT rows per batch: [0..511]   = Hs (v-hat, fp16)
//                        [512..1023]= fp16(v-hat^2)   (hi)
//                        [1024..1535]= v-hat^2 - hi    (lo)  -- protects e2-mean^2
//
// R7 == R6 resubmit (R6 bench was an infra failure, no counters).
// R6: attack the vmcnt-bound profile (R5: MfmaUtil 4.6, VALUBusy 6.1, HBM 1.9,
// VGPR_Count=84 -> ~2 loads in flight/wave; every load is a 16-line gather).
//   * QBLK 16 -> 32 (2 row-tiles/wave): every G fragment feeds 2 logit tiles,
//     every V fragment feeds 2 row-tiles -> MFMA:load ratio 0.8 -> 1.33 and
//     total gather count halves (512 blocks = exactly 2/CU, one round).
//   * Explicit MLP: V fragments for ct=0 issue at tile-loop top (land during
//     QK+softmax); PV issues ct+1's 6 loads before ct's 12 MFMAs.
//   * launch_bounds(256,2): cap 256 >= ~220 demand -> no spill (R4 lesson:
//     cap < demand = scratch catastrophe; tripwire = WRITE_SIZE >> 35MB).
//   Kept: merged e2 hi+lo accumulator (R5), wave-local epilogue, no G/V LDS
//   staging (zero reuse), ~5.6KB LDS, 2 barriers/M-tile.
//   NOTE: every loop touching acc[]/m_run/l_run MUST be fully unrolled --
//   a runtime index demotes the array to scratch (R1/R2 bug).
// ---------------------------------------------------------------------------

typedef _Float16 f16;
typedef _Float16 f16x8 __attribute__((ext_vector_type(8)));
typedef float f32x4 __attribute__((ext_vector_type(4)));

#define LOG2E 1.44269504088896340736f

// ---------------------------------------------------------------------------
// conv_ik: out[b][i][k] = bias[k] + sum_c wm[k][c] * in[b][c][i]   (fp16 out)
// ---------------------------------------------------------------------------
__global__ __launch_bounds__(256, 2) void conv_ik(
    const float* __restrict__ in, const float* __restrict__ wm,
    const float* __restrict__ bias, f16* __restrict__ out) {
  const int i0 = blockIdx.x * 64;
  const int k0 = blockIdx.y * 64;
  const int b = blockIdx.z;
  const int tid = threadIdx.x;
  const int lane = tid & 63;
  const int wv = tid >> 6;
  const int l15 = lane & 15;
  const int quad = lane >> 4;

  __shared__ __align__(16) f16 a_lds[64 * 40];  // [i][c] stride 40 (pad)

  const float* inb = in + (size_t)b * (512 * 4096);

  f32x4 acc[4];
#pragma unroll
  for (int t = 0; t < 4; ++t) acc[t] = f32x4{0.f, 0.f, 0.f, 0.f};

  for (int cs = 0; cs < 512; cs += 32) {
    __syncthreads();
#pragma unroll
    for (int rep = 0; rep < 2; ++rep) {
      int chunk = tid + rep * 256;  // 0..511
      int cc = chunk >> 4;          // 0..31
      int f4 = chunk & 15;          // 0..15
      float4 v = *(const float4*)(inb + (size_t)(cs + cc) * 4096 + i0 + f4 * 4);
      int ib = f4 * 4;
      a_lds[(ib + 0) * 40 + cc] = (f16)v.x;
      a_lds[(ib + 1) * 40 + cc] = (f16)v.y;
      a_lds[(ib + 2) * 40 + cc] = (f16)v.z;
      a_lds[(ib + 3) * 40 + cc] = (f16)v.w;
    }
    __syncthreads();
    f16x8 af = *(const f16x8*)&a_lds[(wv * 16 + l15) * 40 + quad * 8];
#pragma unroll
    for (int ct = 0; ct < 4; ++ct) {
      const float* wp = wm + (size_t)(k0 + ct * 16 + l15) * 512 + cs + quad * 8;
      float4 w0 = *(const float4*)wp;
      float4 w1 = *(const float4*)(wp + 4);
      f16x8 bf;
      bf[0] = (f16)w0.x; bf[1] = (f16)w0.y; bf[2] = (f16)w0.z; bf[3] = (f16)w0.w;
      bf[4] = (f16)w1.x; bf[5] = (f16)w1.y; bf[6] = (f16)w1.z; bf[7] = (f16)w1.w;
      acc[ct] = __builtin_amdgcn_mfma_f32_16x16x32_f16(af, bf, acc[ct], 0, 0, 0);
    }
  }
#pragma unroll
  for (int ct = 0; ct < 4; ++ct) {
    int k = k0 + ct * 16 + l15;
    float bv = bias[k];
#pragma unroll
    for (int r = 0; r < 4; ++r) {
      int i = i0 + wv * 16 + quad * 4 + r;
      out[((size_t)b * 4096 + i) * 512 + k] = (f16)(acc[ct][r] + bv);
    }
  }
}

// ---------------------------------------------------------------------------
// conv_vt: val = bias[k] + sum_c wm[k][c] * in[b][c][i]
//   VT[b][k][i]=fp16(val); VT[b][512+k][i]=hi(val^2); VT[b][1024+k][i]=lo
// ---------------------------------------------------------------------------
__global__ __launch_bounds__(256, 2) void conv_vt(
    const float* __restrict__ in, const float* __restrict__ wm,
    const float* __restrict__ bias, f16* __restrict__ vt) {
  const int i0 = blockIdx.x * 64;
  const int k0 = blockIdx.y * 64;
  const int b = blockIdx.z;
  const int tid = threadIdx.x;
  const int lane = tid & 63;
  const int wv = tid >> 6;
  const int l15 = lane & 15;
  const int quad = lane >> 4;

  __shared__ __align__(16) f16 b_lds[64 * 40];  // [i][c] stride 40

  const float* inb = in + (size_t)b * (512 * 4096);

  f32x4 acc[4];
#pragma unroll
  for (int t = 0; t < 4; ++t) acc[t] = f32x4{0.f, 0.f, 0.f, 0.f};

  for (int cs = 0; cs < 512; cs += 32) {
    __syncthreads();
#pragma unroll
    for (int rep = 0; rep < 2; ++rep) {
      int chunk = tid + rep * 256;
      int cc = chunk >> 4;
      int f4 = chunk & 15;
      float4 v = *(const float4*)(inb + (size_t)(cs + cc) * 4096 + i0 + f4 * 4);
      int ib = f4 * 4;
      b_lds[(ib + 0) * 40 + cc] = (f16)v.x;
      b_lds[(ib + 1) * 40 + cc] = (f16)v.y;
      b_lds[(ib + 2) * 40 + cc] = (f16)v.z;
      b_lds[(ib + 3) * 40 + cc] = (f16)v.w;
    }
    __syncthreads();
    const float* wp = wm + (size_t)(k0 + wv * 16 + l15) * 512 + cs + quad * 8;
    float4 w0 = *(const float4*)wp;
    float4 w1 = *(const float4*)(wp + 4);
    f16x8 af;
    af[0] = (f16)w0.x; af[1] = (f16)w0.y; af[2] = (f16)w0.z; af[3] = (f16)w0.w;
    af[4] = (f16)w1.x; af[5] = (f16)w1.y; af[6] = (f16)w1.z; af[7] = (f16)w1.w;
#pragma unroll
    for (int ct = 0; ct < 4; ++ct) {
      f16x8 bfr = *(const f16x8*)&b_lds[(ct * 16 + l15) * 40 + quad * 8];
      acc[ct] = __builtin_amdgcn_mfma_f32_16x16x32_f16(af, bfr, acc[ct], 0, 0, 0);
    }
  }
  f16* vtb = vt + (size_t)b * 1536 * 4096;
#pragma unroll
  for (int ct = 0; ct < 4; ++ct) {
    int i = i0 + ct * 16 + l15;
#pragma unroll
    for (int r = 0; r < 4; ++r) {
      int k = k0 + wv * 16 + quad * 4 + r;
      float val = acc[ct][r] + bias[k];
      f16 vh = (f16)val;
      float vf = (float)vh;
      float sq = vf * vf;
      f16 sqh = (f16)sq;
      f16 sql = (f16)(sq - (float)sqh);
      vtb[(size_t)k * 4096 + i] = vh;
      vtb[(size_t)(512 + k) * 4096 + i] = sqh;
      vtb[(size_t)(1024 + k) * 4096 + i] = sql;
    }
  }
}

// ---------------------------------------------------------------------------
// adaattn_flash: per block = 32 Q-rows (2 row-tiles) of one batch; 4 waves;
// M-tiles of 64. Wave w owns V channels [w*128, w*128+128):
//   accM0/accE0 = row-tile 0 (rows n0..n0+15), accM1/accE1 = row-tile 1.
//   e2 hi and lo both accumulate into accE* (MFMA C is in/out).
// G fragments shared across both row-tiles; V fragments shared across both
// row-tiles -> half the gather traffic of QBLK=16. Explicit V prefetch:
// ct=0 issues at tile-loop top, PV loads ct+1 before ct's MFMAs.
// Grid 128x4 = 512 blocks = exactly 2/CU, single co-residency round.
// ---------------------------------------------------------------------------
__global__ __launch_bounds__(256, 2) void adaattn_flash(
    const f16* __restrict__ Fb, const f16* __restrict__ Gb,
    const f16* __restrict__ VT, const float* __restrict__ cx,
    float* __restrict__ out) {
  const int n0 = blockIdx.x * 32;
  const int b = blockIdx.y;
  const int tid = threadIdx.x;
  const int lane = tid & 63;
  const int wv = tid >> 6;
  const int l15 = lane & 15;
  const int quad = lane >> 4;

  __shared__ __align__(16) f16 p_lds[32 * 72];  // [qrow 0..31][mcol] stride 72
  __shared__ float smax[128];                   // [wave][qrow 0..31]
  __shared__ float ssum[128];

  // F A-fragment bases, row-tile 0 and 1 (L1-hot 32KB tile)
  const f16* fp0 = Fb + ((size_t)b * 4096 + n0 + l15) * 512 + quad * 8;
  const f16* fp1 = fp0 + (size_t)16 * 512;
  // G B-fragment base for this wave's 16 logit columns (direct global)
  const f16* gq0 = Gb + ((size_t)b * 4096 + wv * 16 + l15) * 512 + quad * 8;
  // V row-group bases: wave's own 128-channel slice of mean / e2hi / e2lo
  const f16* vb0 = VT + ((size_t)b * 1536 + (size_t)wv * 128 + l15) * 4096;
  const f16* vb1 = vb0 + (size_t)512 * 4096;
  const f16* vb2 = vb1 + (size_t)512 * 4096;

  f32x4 accM0[8], accE0[8], accM1[8], accE1[8];
#pragma unroll
  for (int t = 0; t < 8; ++t) {
    accM0[t] = f32x4{0.f, 0.f, 0.f, 0.f};
    accE0[t] = f32x4{0.f, 0.f, 0.f, 0.f};
    accM1[t] = f32x4{0.f, 0.f, 0.f, 0.f};
    accE1[t] = f32x4{0.f, 0.f, 0.f, 0.f};
  }
  float m_run0[4] = {-1e30f, -1e30f, -1e30f, -1e30f};
  float m_run1[4] = {-1e30f, -1e30f, -1e30f, -1e30f};
  float l_run0[4] = {0.f, 0.f, 0.f, 0.f};
  float l_run1[4] = {0.f, 0.f, 0.f, 0.f};

  for (int m0 = 0; m0 < 4096; m0 += 64) {
    // --- issue ct=0 V fragments NOW; they land during QK + softmax ---------
    const f16* vpm = vb0 + m0 + quad * 8;
    const f16* vph = vb1 + m0 + quad * 8;
    const f16* vpl = vb2 + m0 + quad * 8;
    f16x8 vm0 = *(const f16x8*)(vpm);
    f16x8 vm1 = *(const f16x8*)(vpm + 32);
    f16x8 vh0 = *(const f16x8*)(vph);
    f16x8 vh1 = *(const f16x8*)(vph + 32);
    f16x8 vl0 = *(const f16x8*)(vpl);
    f16x8 vl1 = *(const f16x8*)(vpl + 32);

    // --- QK: wave w -> logit cols [w*16,+16) for 32 rows, K=512 ------------
    f32x4 lg0 = f32x4{0.f, 0.f, 0.f, 0.f};
    f32x4 lg1 = f32x4{0.f, 0.f, 0.f, 0.f};
    {
      const f16* gq = gq0 + (size_t)m0 * 512;
#pragma unroll 8
      for (int ks = 0; ks < 16; ++ks) {
        f16x8 gf = *(const f16x8*)(gq + ks * 32);
        f16x8 f0 = *(const f16x8*)(fp0 + ks * 32);
        f16x8 f1 = *(const f16x8*)(fp1 + ks * 32);
        lg0 = __builtin_amdgcn_mfma_f32_16x16x32_f16(f0, gf, lg0, 0, 0, 0);
        lg1 = __builtin_amdgcn_mfma_f32_16x16x32_f16(f1, gf, lg1, 0, 0, 0);
      }
    }

    // --- wave-local row max over this wave's 16 cols -----------------------
#pragma unroll
    for (int r = 0; r < 4; ++r) {
      float v0 = lg0[r], v1 = lg1[r];
      v0 = fmaxf(v0, __shfl_xor(v0, 1));
      v1 = fmaxf(v1, __shfl_xor(v1, 1));
      v0 = fmaxf(v0, __shfl_xor(v0, 2));
      v1 = fmaxf(v1, __shfl_xor(v1, 2));
      v0 = fmaxf(v0, __shfl_xor(v0, 4));
      v1 = fmaxf(v1, __shfl_xor(v1, 4));
      v0 = fmaxf(v0, __shfl_xor(v0, 8));
      v1 = fmaxf(v1, __shfl_xor(v1, 8));
      if (l15 == 0) {
        smax[wv * 32 + quad * 4 + r] = v0;
        smax[wv * 32 + 16 + quad * 4 + r] = v1;
      }
    }
    __syncthreads();  // bar1: smax complete; fences prev-iter p_lds reads

    float alpha0[4], alpha1[4], ts0[4], ts1[4];
#pragma unroll
    for (int r = 0; r < 4; ++r) {
      {  // row-tile 0
        int row = quad * 4 + r;
        float mt = fmaxf(fmaxf(smax[row], smax[32 + row]),
                         fmaxf(smax[64 + row], smax[96 + row]));
        float mn = fmaxf(m_run0[r], mt);
        alpha0[r] = exp2f((m_run0[r] - mn) * LOG2E);
        m_run0[r] = mn;
        float p = exp2f((lg0[r] - mn) * LOG2E);
        f16 ph = (f16)p;  // round first so weights & sums agree exactly
        p = (float)ph;
        p_lds[row * 72 + wv * 16 + l15] = ph;
        float s = p;
        s += __shfl_xor(s, 1);
        s += __shfl_xor(s, 2);
        s += __shfl_xor(s, 4);
        s += __shfl_xor(s, 8);
        ts0[r] = s;
      }
      {  // row-tile 1
        int row = 16 + quad * 4 + r;
        float mt = fmaxf(fmaxf(smax[row], smax[32 + row]),
                         fmaxf(smax[64 + row], smax[96 + row]));
        float mn = fmaxf(m_run1[r], mt);
        alpha1[r] = exp2f((m_run1[r] - mn) * LOG2E);
        m_run1[r] = mn;
        float p = exp2f((lg1[r] - mn) * LOG2E);
        f16 ph = (f16)p;
        p = (float)ph;
        p_lds[row * 72 + wv * 16 + l15] = ph;
        float s = p;
        s += __shfl_xor(s, 1);
        s += __shfl_xor(s, 2);
        s += __shfl_xor(s, 4);
        s += __shfl_xor(s, 8);
        ts1[r] = s;
      }
    }
    if (l15 == 0) {
#pragma unroll
      for (int r = 0; r < 4; ++r) {
        ssum[wv * 32 + quad * 4 + r] = ts0[r];
        ssum[wv * 32 + 16 + quad * 4 + r] = ts1[r];
      }
    }
    // rescale accumulators by alpha (per-row); skip when all alpha == 1
    if (__any(alpha0[0] != 1.f || alpha0[1] != 1.f ||
              alpha0[2] != 1.f || alpha0[3] != 1.f ||
              alpha1[0] != 1.f || alpha1[1] != 1.f ||
              alpha1[2] != 1.f || alpha1[3] != 1.f)) {
#pragma unroll
      for (int t = 0; t < 8; ++t) {
#pragma unroll
        for (int r = 0; r < 4; ++r) {
          accM0[t][r] *= alpha0[r];
          accE0[t][r] *= alpha0[r];
          accM1[t][r] *= alpha1[r];
          accE1[t][r] *= alpha1[r];
        }
      }
    }
    __syncthreads();  // bar2: p_lds + ssum complete

#pragma unroll
    for (int r = 0; r < 4; ++r) {
      int row = quad * 4 + r;
      l_run0[r] = l_run0[r] * alpha0[r] +
                  (ssum[row] + ssum[32 + row] + ssum[64 + row] + ssum[96 + row]);
      l_run1[r] = l_run1[r] * alpha1[r] +
                  (ssum[16 + row] + ssum[48 + row] + ssum[80 + row] + ssum[112 + row]);
    }

    // --- PV: A = P (LDS), B = VT direct global; explicit +1 prefetch -------
    f16x8 pf00 = *(const f16x8*)&p_lds[l15 * 72 + quad * 8];
    f16x8 pf01 = *(const f16x8*)&p_lds[l15 * 72 + 32 + quad * 8];
    f16x8 pf10 = *(const f16x8*)&p_lds[(16 + l15) * 72 + quad * 8];
    f16x8 pf11 = *(const f16x8*)&p_lds[(16 + l15) * 72 + 32 + quad * 8];
#pragma unroll
    for (int ct = 0; ct < 8; ++ct) {
      f16x8 nm0 = vm0, nm1 = vm1, nh0 = vh0, nh1 = vh1, nl0 = vl0, nl1 = vl1;
      if (ct < 7) {  // compile-time in unrolled body
        const size_t o = (size_t)(ct + 1) * (16 * 4096);
        nm0 = *(const f16x8*)(vpm + o);
        nm1 = *(const f16x8*)(vpm + o + 32);
        nh0 = *(const f16x8*)(vph + o);
        nh1 = *(const f16x8*)(vph + o + 32);
        nl0 = *(const f16x8*)(vpl + o);
        nl1 = *(const f16x8*)(vpl + o + 32);
      }
      accM0[ct] = __builtin_amdgcn_mfma_f32_16x16x32_f16(pf00, vm0, accM0[ct], 0, 0, 0);
      accM0[ct] = __builtin_amdgcn_mfma_f32_16x16x32_f16(pf01, vm1, accM0[ct], 0, 0, 0);
      accM1[ct] = __builtin_amdgcn_mfma_f32_16x16x32_f16(pf10, vm0, accM1[ct], 0, 0, 0);
      accM1[ct] = __builtin_amdgcn_mfma_f32_16x16x32_f16(pf11, vm1, accM1[ct], 0, 0, 0);
      accE0[ct] = __builtin_amdgcn_mfma_f32_16x16x32_f16(pf00, vh0, accE0[ct], 0, 0, 0);
      accE0[ct] = __builtin_amdgcn_mfma_f32_16x16x32_f16(pf01, vh1, accE0[ct], 0, 0, 0);
      accE1[ct] = __builtin_amdgcn_mfma_f32_16x16x32_f16(pf10, vh0, accE1[ct], 0, 0, 0);
      accE1[ct] = __builtin_amdgcn_mfma_f32_16x16x32_f16(pf11, vh1, accE1[ct], 0, 0, 0);
      accE0[ct] = __builtin_amdgcn_mfma_f32_16x16x32_f16(pf00, vl0, accE0[ct], 0, 0, 0);
      accE0[ct] = __builtin_amdgcn_mfma_f32_16x16x32_f16(pf01, vl1, accE0[ct], 0, 0, 0);
      accE1[ct] = __builtin_amdgcn_mfma_f32_16x16x32_f16(pf10, vl0, accE1[ct], 0, 0, 0);
      accE1[ct] = __builtin_amdgcn_mfma_f32_16x16x32_f16(pf11, vl1, accE1[ct], 0, 0, 0);
      vm0 = nm0; vm1 = nm1; vh0 = nh0; vh1 = nh1; vl0 = nl0; vl1 = nl1;
    }
  }

  // ---------------- epilogue (wave-local, no LDS, no barriers) ------------
  float inv0[4], inv1[4];
#pragma unroll
  for (int r = 0; r < 4; ++r) {
    inv0[r] = 1.0f / l_run0[r];
    inv1[r] = 1.0f / l_run1[r];
  }

  const size_t base = ((size_t)b * 512) * 4096 + n0 + quad * 4;
#pragma unroll
  for (int ct = 0; ct < 8; ++ct) {
    int c = wv * 128 + ct * 16 + l15;
    size_t off0 = base + (size_t)c * 4096;
    size_t off1 = off0 + 16;
    f32x4 cxv0 = *(const f32x4*)(cx + off0);
    f32x4 cxv1 = *(const f32x4*)(cx + off1);
    f32x4 o0, o1;
#pragma unroll
    for (int r = 0; r < 4; ++r) {
      float m = accM0[ct][r] * inv0[r];
      float e2 = accE0[ct][r] * inv0[r];
      float sd = sqrtf(fmaxf(e2 - m * m, 0.f));
      o0[r] = sd * cxv0[r] + m;
      float m1 = accM1[ct][r] * inv1[r];
      float e21 = accE1[ct][r] * inv1[r];
      float sd1 = sqrtf(fmaxf(e21 - m1 * m1, 0.f));
      o1[r] = sd1 * cxv1[r] + m1;
    }
    *(f32x4*)(out + off0) = o0;
    *(f32x4*)(out + off1) = o1;
  }
}

// ---------------------------------------------------------------------------
extern "C" void kernel_launch(void* const* d_in, const int* in_sizes, int n_in,
                              void* d_out, int out_size, void* d_ws, size_t ws_size,
                              hipStream_t stream) {
  (void)in_sizes; (void)n_in; (void)out_size;
  const float* c_x  = (const float*)d_in[0];
  const float* s_x  = (const float*)d_in[1];
  const float* c_1x = (const float*)d_in[2];
  const float* s_1x = (const float*)d_in[3];
  const float* f_w  = (const float*)d_in[4];
  const float* f_b  = (const float*)d_in[5];
  const float* g_w  = (const float*)d_in[6];
  const float* g_b  = (const float*)d_in[7];
  const float* h_w  = (const float*)d_in[8];
  const float* h_b  = (const float*)d_in[9];
  float* out = (float*)d_out;

  const size_t fe = (size_t)4 * 4096 * 512;  // elements per F/G buffer
  f16* Fb = (f16*)d_ws;
  f16* Gb = Fb + fe;
  f16* VT = Gb + fe;
  const size_t need = fe * 2 * sizeof(f16) * 2 + (size_t)4 * 1536 * 4096 * sizeof(f16);
  if (ws_size < need) return;  // 80 MiB required; fail loudly (output stays poisoned)

  dim3 blk(256);
  dim3 gP(64, 8, 4);
  conv_ik<<<gP, blk, 0, stream>>>(c_1x, f_w, f_b, Fb);
  conv_ik<<<gP, blk, 0, stream>>>(s_1x, g_w, g_b, Gb);
  conv_vt<<<gP, blk, 0, stream>>>(s_x, h_w, h_b, VT);
  adaattn_flash<<<dim3(128, 4), blk, 0, stream>>>(Fb, Gb, VT, c_x, out);
}

// Round 5
// 2091.906 us; speedup vs baseline: 1.7101x; 1.0915x over previous
//
#include <hip/hip_runtime.h>
#include <cstdint>
#include <cstddef>

// ---------------------------------------------------------------------------
// AdaAttN fused kernel set, fp16 MFMA path.
//   B=4, C=KP=512, N=M=4096.
//   ws layout (fp16): Fb[4][4096][512] | Gb[4][4096][512] | VT[4][1536][4096]
//     VT rows per batch: [0..511]   = Hs (v-hat, fp16)
//                        [512..1023]= fp16(v-hat^2)   (hi)
//                        [1024..1535]= v-hat^2 - hi    (lo)  -- protects e2-mean^2
//
// R8: QBLK=32 reuse structure (R7) + R5's spill-free load discipline.
//   R7 post-mortem: V-fragment double-buffer (cur 24 + next 24 regs) + early
//   ct=0 issue pushed arch-VGPR demand past the 128/128 VGPR/AGPR split at
//   the (256,2) cap -> 2.3 GB scratch writes/dispatch; the whole 1900 us was
//   scratch BW. R5 proved per-ct load->consume fits (VGPR 84, zero spill).
//   * PV: per-ct, 6 loads then 12 MFMAs; no rotation, no early issue.
//   * Keep: QBLK=32 (G and V fragments each feed 2 row-tiles -> half the
//     gather count of QBLK=16), merged e2 hi+lo accumulator, wave-local
//     epilogue, no G/V LDS staging, ~5.6KB LDS, 2 barriers/M-tile,
//     launch_bounds(256,2). Grid 128x4 = 512 blocks = 2/CU.
//   NOTE: every loop touching acc[]/m_run/l_run MUST be fully unrolled --
//   a runtime index demotes the array to scratch (R1/R2 bug).
//   Spill tripwire: WRITE_SIZE >> 40 MB per dispatch.
// ---------------------------------------------------------------------------

typedef _Float16 f16;
typedef _Float16 f16x8 __attribute__((ext_vector_type(8)));
typedef float f32x4 __attribute__((ext_vector_type(4)));

#define LOG2E 1.44269504088896340736f

// ---------------------------------------------------------------------------
// conv_ik: out[b][i][k] = bias[k] + sum_c wm[k][c] * in[b][c][i]   (fp16 out)
// ---------------------------------------------------------------------------
__global__ __launch_bounds__(256, 2) void conv_ik(
    const float* __restrict__ in, const float* __restrict__ wm,
    const float* __restrict__ bias, f16* __restrict__ out) {
  const int i0 = blockIdx.x * 64;
  const int k0 = blockIdx.y * 64;
  const int b = blockIdx.z;
  const int tid = threadIdx.x;
  const int lane = tid & 63;
  const int wv = tid >> 6;
  const int l15 = lane & 15;
  const int quad = lane >> 4;

  __shared__ __align__(16) f16 a_lds[64 * 40];  // [i][c] stride 40 (pad)

  const float* inb = in + (size_t)b * (512 * 4096);

  f32x4 acc[4];
#pragma unroll
  for (int t = 0; t < 4; ++t) acc[t] = f32x4{0.f, 0.f, 0.f, 0.f};

  for (int cs = 0; cs < 512; cs += 32) {
    __syncthreads();
#pragma unroll
    for (int rep = 0; rep < 2; ++rep) {
      int chunk = tid + rep * 256;  // 0..511
      int cc = chunk >> 4;          // 0..31
      int f4 = chunk & 15;          // 0..15
      float4 v = *(const float4*)(inb + (size_t)(cs + cc) * 4096 + i0 + f4 * 4);
      int ib = f4 * 4;
      a_lds[(ib + 0) * 40 + cc] = (f16)v.x;
      a_lds[(ib + 1) * 40 + cc] = (f16)v.y;
      a_lds[(ib + 2) * 40 + cc] = (f16)v.z;
      a_lds[(ib + 3) * 40 + cc] = (f16)v.w;
    }
    __syncthreads();
    f16x8 af = *(const f16x8*)&a_lds[(wv * 16 + l15) * 40 + quad * 8];
#pragma unroll
    for (int ct = 0; ct < 4; ++ct) {
      const float* wp = wm + (size_t)(k0 + ct * 16 + l15) * 512 + cs + quad * 8;
      float4 w0 = *(const float4*)wp;
      float4 w1 = *(const float4*)(wp + 4);
      f16x8 bf;
      bf[0] = (f16)w0.x; bf[1] = (f16)w0.y; bf[2] = (f16)w0.z; bf[3] = (f16)w0.w;
      bf[4] = (f16)w1.x; bf[5] = (f16)w1.y; bf[6] = (f16)w1.z; bf[7] = (f16)w1.w;
      acc[ct] = __builtin_amdgcn_mfma_f32_16x16x32_f16(af, bf, acc[ct], 0, 0, 0);
    }
  }
#pragma unroll
  for (int ct = 0; ct < 4; ++ct) {
    int k = k0 + ct * 16 + l15;
    float bv = bias[k];
#pragma unroll
    for (int r = 0; r < 4; ++r) {
      int i = i0 + wv * 16 + quad * 4 + r;
      out[((size_t)b * 4096 + i) * 512 + k] = (f16)(acc[ct][r] + bv);
    }
  }
}

// ---------------------------------------------------------------------------
// conv_vt: val = bias[k] + sum_c wm[k][c] * in[b][c][i]
//   VT[b][k][i]=fp16(val); VT[b][512+k][i]=hi(val^2); VT[b][1024+k][i]=lo
// ---------------------------------------------------------------------------
__global__ __launch_bounds__(256, 2) void conv_vt(
    const float* __restrict__ in, const float* __restrict__ wm,
    const float* __restrict__ bias, f16* __restrict__ vt) {
  const int i0 = blockIdx.x * 64;
  const int k0 = blockIdx.y * 64;
  const int b = blockIdx.z;
  const int tid = threadIdx.x;
  const int lane = tid & 63;
  const int wv = tid >> 6;
  const int l15 = lane & 15;
  const int quad = lane >> 4;

  __shared__ __align__(16) f16 b_lds[64 * 40];  // [i][c] stride 40

  const float* inb = in + (size_t)b * (512 * 4096);

  f32x4 acc[4];
#pragma unroll
  for (int t = 0; t < 4; ++t) acc[t] = f32x4{0.f, 0.f, 0.f, 0.f};

  for (int cs = 0; cs < 512; cs += 32) {
    __syncthreads();
#pragma unroll
    for (int rep = 0; rep < 2; ++rep) {
      int chunk = tid + rep * 256;
      int cc = chunk >> 4;
      int f4 = chunk & 15;
      float4 v = *(const float4*)(inb + (size_t)(cs + cc) * 4096 + i0 + f4 * 4);
      int ib = f4 * 4;
      b_lds[(ib + 0) * 40 + cc] = (f16)v.x;
      b_lds[(ib + 1) * 40 + cc] = (f16)v.y;
      b_lds[(ib + 2) * 40 + cc] = (f16)v.z;
      b_lds[(ib + 3) * 40 + cc] = (f16)v.w;
    }
    __syncthreads();
    const float* wp = wm + (size_t)(k0 + wv * 16 + l15) * 512 + cs + quad * 8;
    float4 w0 = *(const float4*)wp;
    float4 w1 = *(const float4*)(wp + 4);
    f16x8 af;
    af[0] = (f16)w0.x; af[1] = (f16)w0.y; af[2] = (f16)w0.z; af[3] = (f16)w0.w;
    af[4] = (f16)w1.x; af[5] = (f16)w1.y; af[6] = (f16)w1.z; af[7] = (f16)w1.w;
#pragma unroll
    for (int ct = 0; ct < 4; ++ct) {
      f16x8 bfr = *(const f16x8*)&b_lds[(ct * 16 + l15) * 40 + quad * 8];
      acc[ct] = __builtin_amdgcn_mfma_f32_16x16x32_f16(af, bfr, acc[ct], 0, 0, 0);
    }
  }
  f16* vtb = vt + (size_t)b * 1536 * 4096;
#pragma unroll
  for (int ct = 0; ct < 4; ++ct) {
    int i = i0 + ct * 16 + l15;
#pragma unroll
    for (int r = 0; r < 4; ++r) {
      int k = k0 + wv * 16 + quad * 4 + r;
      float val = acc[ct][r] + bias[k];
      f16 vh = (f16)val;
      float vf = (float)vh;
      float sq = vf * vf;
      f16 sqh = (f16)sq;
      f16 sql = (f16)(sq - (float)sqh);
      vtb[(size_t)k * 4096 + i] = vh;
      vtb[(size_t)(512 + k) * 4096 + i] = sqh;
      vtb[(size_t)(1024 + k) * 4096 + i] = sql;
    }
  }
}

// ---------------------------------------------------------------------------
// adaattn_flash: per block = 32 Q-rows (2 row-tiles) of one batch; 4 waves;
// M-tiles of 64. Wave w owns V channels [w*128, w*128+128):
//   accM0/accE0 = row-tile 0 (rows n0..n0+15), accM1/accE1 = row-tile 1.
//   e2 hi and lo both accumulate into accE* (MFMA C is in/out).
// G fragments shared across both row-tiles; V fragments shared across both
// row-tiles -> half the gather traffic of QBLK=16. PV loads are per-ct
// (6 loads -> 12 MFMAs): short live ranges, no spill (R7 lesson).
// Grid 128x4 = 512 blocks = exactly 2/CU, single co-residency round.
// ---------------------------------------------------------------------------
__global__ __launch_bounds__(256, 2) void adaattn_flash(
    const f16* __restrict__ Fb, const f16* __restrict__ Gb,
    const f16* __restrict__ VT, const float* __restrict__ cx,
    float* __restrict__ out) {
  const int n0 = blockIdx.x * 32;
  const int b = blockIdx.y;
  const int tid = threadIdx.x;
  const int lane = tid & 63;
  const int wv = tid >> 6;
  const int l15 = lane & 15;
  const int quad = lane >> 4;

  __shared__ __align__(16) f16 p_lds[32 * 72];  // [qrow 0..31][mcol] stride 72
  __shared__ float smax[128];                   // [wave][qrow 0..31]
  __shared__ float ssum[128];

  // F A-fragment bases, row-tile 0 and 1 (L1-hot 32KB tile)
  const f16* fp0 = Fb + ((size_t)b * 4096 + n0 + l15) * 512 + quad * 8;
  const f16* fp1 = fp0 + (size_t)16 * 512;
  // G B-fragment base for this wave's 16 logit columns (direct global)
  const f16* gq0 = Gb + ((size_t)b * 4096 + wv * 16 + l15) * 512 + quad * 8;
  // V row-group bases: wave's own 128-channel slice of mean / e2hi / e2lo
  const f16* vb0 = VT + ((size_t)b * 1536 + (size_t)wv * 128 + l15) * 4096;
  const f16* vb1 = vb0 + (size_t)512 * 4096;
  const f16* vb2 = vb1 + (size_t)512 * 4096;

  f32x4 accM0[8], accE0[8], accM1[8], accE1[8];
#pragma unroll
  for (int t = 0; t < 8; ++t) {
    accM0[t] = f32x4{0.f, 0.f, 0.f, 0.f};
    accE0[t] = f32x4{0.f, 0.f, 0.f, 0.f};
    accM1[t] = f32x4{0.f, 0.f, 0.f, 0.f};
    accE1[t] = f32x4{0.f, 0.f, 0.f, 0.f};
  }
  float m_run0[4] = {-1e30f, -1e30f, -1e30f, -1e30f};
  float m_run1[4] = {-1e30f, -1e30f, -1e30f, -1e30f};
  float l_run0[4] = {0.f, 0.f, 0.f, 0.f};
  float l_run1[4] = {0.f, 0.f, 0.f, 0.f};

  for (int m0 = 0; m0 < 4096; m0 += 64) {
    // --- QK: wave w -> logit cols [w*16,+16) for 32 rows, K=512 ------------
    f32x4 lg0 = f32x4{0.f, 0.f, 0.f, 0.f};
    f32x4 lg1 = f32x4{0.f, 0.f, 0.f, 0.f};
    {
      const f16* gq = gq0 + (size_t)m0 * 512;
#pragma unroll 8
      for (int ks = 0; ks < 16; ++ks) {
        f16x8 gf = *(const f16x8*)(gq + ks * 32);
        f16x8 f0 = *(const f16x8*)(fp0 + ks * 32);
        f16x8 f1 = *(const f16x8*)(fp1 + ks * 32);
        lg0 = __builtin_amdgcn_mfma_f32_16x16x32_f16(f0, gf, lg0, 0, 0, 0);
        lg1 = __builtin_amdgcn_mfma_f32_16x16x32_f16(f1, gf, lg1, 0, 0, 0);
      }
    }

    // --- wave-local row max over this wave's 16 cols -----------------------
#pragma unroll
    for (int r = 0; r < 4; ++r) {
      float v0 = lg0[r], v1 = lg1[r];
      v0 = fmaxf(v0, __shfl_xor(v0, 1));
      v1 = fmaxf(v1, __shfl_xor(v1, 1));
      v0 = fmaxf(v0, __shfl_xor(v0, 2));
      v1 = fmaxf(v1, __shfl_xor(v1, 2));
      v0 = fmaxf(v0, __shfl_xor(v0, 4));
      v1 = fmaxf(v1, __shfl_xor(v1, 4));
      v0 = fmaxf(v0, __shfl_xor(v0, 8));
      v1 = fmaxf(v1, __shfl_xor(v1, 8));
      if (l15 == 0) {
        smax[wv * 32 + quad * 4 + r] = v0;
        smax[wv * 32 + 16 + quad * 4 + r] = v1;
      }
    }
    __syncthreads();  // bar1: smax complete; fences prev-iter p_lds reads

    float alpha0[4], alpha1[4], ts0[4], ts1[4];
#pragma unroll
    for (int r = 0; r < 4; ++r) {
      {  // row-tile 0
        int row = quad * 4 + r;
        float mt = fmaxf(fmaxf(smax[row], smax[32 + row]),
                         fmaxf(smax[64 + row], smax[96 + row]));
        float mn = fmaxf(m_run0[r], mt);
        alpha0[r] = exp2f((m_run0[r] - mn) * LOG2E);
        m_run0[r] = mn;
        float p = exp2f((lg0[r] - mn) * LOG2E);
        f16 ph = (f16)p;  // round first so weights & sums agree exactly
        p = (float)ph;
        p_lds[row * 72 + wv * 16 + l15] = ph;
        float s = p;
        s += __shfl_xor(s, 1);
        s += __shfl_xor(s, 2);
        s += __shfl_xor(s, 4);
        s += __shfl_xor(s, 8);
        ts0[r] = s;
      }
      {  // row-tile 1
        int row = 16 + quad * 4 + r;
        float mt = fmaxf(fmaxf(smax[row], smax[32 + row]),
                         fmaxf(smax[64 + row], smax[96 + row]));
        float mn = fmaxf(m_run1[r], mt);
        alpha1[r] = exp2f((m_run1[r] - mn) * LOG2E);
        m_run1[r] = mn;
        float p = exp2f((lg1[r] - mn) * LOG2E);
        f16 ph = (f16)p;
        p = (float)ph;
        p_lds[row * 72 + wv * 16 + l15] = ph;
        float s = p;
        s += __shfl_xor(s, 1);
        s += __shfl_xor(s, 2);
        s += __shfl_xor(s, 4);
        s += __shfl_xor(s, 8);
        ts1[r] = s;
      }
    }
    if (l15 == 0) {
#pragma unroll
      for (int r = 0; r < 4; ++r) {
        ssum[wv * 32 + quad * 4 + r] = ts0[r];
        ssum[wv * 32 + 16 + quad * 4 + r] = ts1[r];
      }
    }
    // rescale accumulators by alpha (per-row); skip when all alpha == 1
    if (__any(alpha0[0] != 1.f || alpha0[1] != 1.f ||
              alpha0[2] != 1.f || alpha0[3] != 1.f ||
              alpha1[0] != 1.f || alpha1[1] != 1.f ||
              alpha1[2] != 1.f || alpha1[3] != 1.f)) {
#pragma unroll
      for (int t = 0; t < 8; ++t) {
#pragma unroll
        for (int r = 0; r < 4; ++r) {
          accM0[t][r] *= alpha0[r];
          accE0[t][r] *= alpha0[r];
          accM1[t][r] *= alpha1[r];
          accE1[t][r] *= alpha1[r];
        }
      }
    }
    __syncthreads();  // bar2: p_lds + ssum complete

#pragma unroll
    for (int r = 0; r < 4; ++r) {
      int row = quad * 4 + r;
      l_run0[r] = l_run0[r] * alpha0[r] +
                  (ssum[row] + ssum[32 + row] + ssum[64 + row] + ssum[96 + row]);
      l_run1[r] = l_run1[r] * alpha1[r] +
                  (ssum[16 + row] + ssum[48 + row] + ssum[80 + row] + ssum[112 + row]);
    }

    // --- PV: A = P (LDS), B = VT direct global; per-ct loads (no rotation) -
    f16x8 pf00 = *(const f16x8*)&p_lds[l15 * 72 + quad * 8];
    f16x8 pf01 = *(const f16x8*)&p_lds[l15 * 72 + 32 + quad * 8];
    f16x8 pf10 = *(const f16x8*)&p_lds[(16 + l15) * 72 + quad * 8];
    f16x8 pf11 = *(const f16x8*)&p_lds[(16 + l15) * 72 + 32 + quad * 8];
    const f16* vpm = vb0 + m0 + quad * 8;
    const f16* vph = vb1 + m0 + quad * 8;
    const f16* vpl = vb2 + m0 + quad * 8;
#pragma unroll
    for (int ct = 0; ct < 8; ++ct) {
      const size_t o = (size_t)ct * (16 * 4096);
      f16x8 vm0 = *(const f16x8*)(vpm + o);
      f16x8 vm1 = *(const f16x8*)(vpm + o + 32);
      f16x8 vh0 = *(const f16x8*)(vph + o);
      f16x8 vh1 = *(const f16x8*)(vph + o + 32);
      f16x8 vl0 = *(const f16x8*)(vpl + o);
      f16x8 vl1 = *(const f16x8*)(vpl + o + 32);
      accM0[ct] = __builtin_amdgcn_mfma_f32_16x16x32_f16(pf00, vm0, accM0[ct], 0, 0, 0);
      accM0[ct] = __builtin_amdgcn_mfma_f32_16x16x32_f16(pf01, vm1, accM0[ct], 0, 0, 0);
      accM1[ct] = __builtin_amdgcn_mfma_f32_16x16x32_f16(pf10, vm0, accM1[ct], 0, 0, 0);
      accM1[ct] = __builtin_amdgcn_mfma_f32_16x16x32_f16(pf11, vm1, accM1[ct], 0, 0, 0);
      accE0[ct] = __builtin_amdgcn_mfma_f32_16x16x32_f16(pf00, vh0, accE0[ct], 0, 0, 0);
      accE0[ct] = __builtin_amdgcn_mfma_f32_16x16x32_f16(pf01, vh1, accE0[ct], 0, 0, 0);
      accE1[ct] = __builtin_amdgcn_mfma_f32_16x16x32_f16(pf10, vh0, accE1[ct], 0, 0, 0);
      accE1[ct] = __builtin_amdgcn_mfma_f32_16x16x32_f16(pf11, vh1, accE1[ct], 0, 0, 0);
      accE0[ct] = __builtin_amdgcn_mfma_f32_16x16x32_f16(pf00, vl0, accE0[ct], 0, 0, 0);
      accE0[ct] = __builtin_amdgcn_mfma_f32_16x16x32_f16(pf01, vl1, accE0[ct], 0, 0, 0);
      accE1[ct] = __builtin_amdgcn_mfma_f32_16x16x32_f16(pf10, vl0, accE1[ct], 0, 0, 0);
      accE1[ct] = __builtin_amdgcn_mfma_f32_16x16x32_f16(pf11, vl1, accE1[ct], 0, 0, 0);
    }
  }

  // ---------------- epilogue (wave-local, no LDS, no barriers) ------------
  float inv0[4], inv1[4];
#pragma unroll
  for (int r = 0; r < 4; ++r) {
    inv0[r] = 1.0f / l_run0[r];
    inv1[r] = 1.0f / l_run1[r];
  }

  const size_t base = ((size_t)b * 512) * 4096 + n0 + quad * 4;
#pragma unroll
  for (int ct = 0; ct < 8; ++ct) {
    int c = wv * 128 + ct * 16 + l15;
    size_t off0 = base + (size_t)c * 4096;
    size_t off1 = off0 + 16;
    f32x4 cxv0 = *(const f32x4*)(cx + off0);
    f32x4 cxv1 = *(const f32x4*)(cx + off1);
    f32x4 o0, o1;
#pragma unroll
    for (int r = 0; r < 4; ++r) {
      float m = accM0[ct][r] * inv0[r];
      float e2 = accE0[ct][r] * inv0[r];
      float sd = sqrtf(fmaxf(e2 - m * m, 0.f));
      o0[r] = sd * cxv0[r] + m;
      float m1 = accM1[ct][r] * inv1[r];
      float e21 = accE1[ct][r] * inv1[r];
      float sd1 = sqrtf(fmaxf(e21 - m1 * m1, 0.f));
      o1[r] = sd1 * cxv1[r] + m1;
    }
    *(f32x4*)(out + off0) = o0;
    *(f32x4*)(out + off1) = o1;
  }
}

// ---------------------------------------------------------------------------
extern "C" void kernel_launch(void* const* d_in, const int* in_sizes, int n_in,
                              void* d_out, int out_size, void* d_ws, size_t ws_size,
                              hipStream_t stream) {
  (void)in_sizes; (void)n_in; (void)out_size;
  const float* c_x  = (const float*)d_in[0];
  const float* s_x  = (const float*)d_in[1];
  const float* c_1x = (const float*)d_in[2];
  const float* s_1x = (const float*)d_in[3];
  const float* f_w  = (const float*)d_in[4];
  const float* f_b  = (const float*)d_in[5];
  const float* g_w  = (const float*)d_in[6];
  const float* g_b  = (const float*)d_in[7];
  const float* h_w  = (const float*)d_in[8];
  const float* h_b  = (const float*)d_in[9];
  float* out = (float*)d_out;

  const size_t fe = (size_t)4 * 4096 * 512;  // elements per F/G buffer
  f16* Fb = (f16*)d_ws;
  f16* Gb = Fb + fe;
  f16* VT = Gb + fe;
  const size_t need = fe * 2 * sizeof(f16) * 2 + (size_t)4 * 1536 * 4096 * sizeof(f16);
  if (ws_size < need) return;  // 80 MiB required; fail loudly (output stays poisoned)

  dim3 blk(256);
  dim3 gP(64, 8, 4);
  conv_ik<<<gP, blk, 0, stream>>>(c_1x, f_w, f_b, Fb);
  conv_ik<<<gP, blk, 0, stream>>>(s_1x, g_w, g_b, Gb);
  conv_vt<<<gP, blk, 0, stream>>>(s_x, h_w, h_b, VT);
  adaattn_flash<<<dim3(128, 4), blk, 0, stream>>>(Fb, Gb, VT, c_x, out);
}